// Round 7
// baseline (332.670 us; speedup 1.0000x reference)
//
#include <hip/hip_runtime.h>
#include <hip/hip_bf16.h>
#include <math.h>

#define BB 2
#define SS 2048
#define EE 2048
#define NQ 16
#define NKV 4
#define HD 128
#define WINDOW 512

typedef __hip_bfloat16 bf16;
typedef short short8 __attribute__((ext_vector_type(8)));   // 8 bf16 (4 VGPRs)
typedef float f32x4 __attribute__((ext_vector_type(4)));

__device__ __forceinline__ float toF(bf16 v) { return __bfloat162float(v); }
__device__ __forceinline__ bf16 toB(float v) { return __float2bfloat16(v); }

// async global->LDS, 16B per lane. LDS dest = wave-uniform base + lane*16.
__device__ __forceinline__ void gld_lds16(const void* g, void* l) {
    __builtin_amdgcn_global_load_lds(
        (const __attribute__((address_space(1))) void*)g,
        (__attribute__((address_space(3))) void*)l, 16, 0, 0);
}

// ---------------------------------------------------------------------------
// fp32 -> bf16 elementwise (n % 4 == 0)
// ---------------------------------------------------------------------------
__global__ __launch_bounds__(256) void convert_bf16(const float* __restrict__ in,
                                                    bf16* __restrict__ out, int n) {
    int i = (blockIdx.x * 256 + threadIdx.x) * 4;
    if (i >= n) return;
    const float4 v = *(const float4*)(in + i);
    bf16 o[4] = {toB(v.x), toB(v.y), toB(v.z), toB(v.w)};
    *(uint2*)(out + i) = *(const uint2*)o;
}

// ---------------------------------------------------------------------------
// fp32 [K][N] -> bf16 [N][K] transpose. Generic (Wo).
// ---------------------------------------------------------------------------
__global__ __launch_bounds__(256) void convert_transpose(const float* __restrict__ in,
                                                         bf16* __restrict__ out,
                                                         int K, int N) {
    __shared__ float tile[32][33];
    const int t = threadIdx.x;
    const int tx = t & 31, ty = t >> 5;   // 32 x 8
    const int n0 = blockIdx.x * 32, k0 = blockIdx.y * 32;
#pragma unroll
    for (int r = 0; r < 4; r++)
        tile[ty + r * 8][tx] = in[(size_t)(k0 + ty + r * 8) * N + n0 + tx];
    __syncthreads();
#pragma unroll
    for (int r = 0; r < 4; r++)
        out[(size_t)(n0 + ty + r * 8) * K + k0 + tx] = toB(tile[tx][ty + r * 8]);
}

// ---------------------------------------------------------------------------
// Fused Wq/Wk/Wv transpose into packed [3072][2048] bf16.
// ---------------------------------------------------------------------------
__global__ __launch_bounds__(256) void convert_transpose_qkv(
    const float* __restrict__ Wq, const float* __restrict__ Wk,
    const float* __restrict__ Wv, bf16* __restrict__ out) {
    __shared__ float tile[32][33];
    const int t = threadIdx.x;
    const int tx = t & 31, ty = t >> 5;
    const int n0 = blockIdx.x * 32, k0 = blockIdx.y * 32;
    const float* src; int N, nl0;
    if (n0 < 2048)      { src = Wq; N = 2048; nl0 = n0; }
    else if (n0 < 2560) { src = Wk; N = 512;  nl0 = n0 - 2048; }
    else                { src = Wv; N = 512;  nl0 = n0 - 2560; }
#pragma unroll
    for (int r = 0; r < 4; r++)
        tile[ty + r * 8][tx] = src[(size_t)(k0 + ty + r * 8) * N + nl0 + tx];
    __syncthreads();
#pragma unroll
    for (int r = 0; r < 4; r++)
        out[(size_t)(n0 + ty + r * 8) * 2048 + k0 + tx] = toB(tile[tx][ty + r * 8]);
}

// ---------------------------------------------------------------------------
// MFMA bf16 GEMM (m97 structure), 128x128 tile, BK=32, XOR-swizzled LDS.
// MODE 0: fp32 out + bias.
// MODE 1: packed QKV: Q (pre-scaled by 1/sqrt(HD)) + RoPE -> Yq[b,s,h,d];
//         K + RoPE -> Yk[b,s,hkv,d]; V -> TRANSPOSED Yv[b,hkv,d,s].
// ---------------------------------------------------------------------------
template <int MODE>
__global__ __launch_bounds__(256) void mfma_gemm(
    const bf16* __restrict__ A, const bf16* __restrict__ BT,
    const float* __restrict__ b0, const float* __restrict__ b1,
    const float* __restrict__ b2,
    float* __restrict__ Yf,
    bf16* __restrict__ Yq, bf16* __restrict__ Yk, bf16* __restrict__ Yv,
    int M, int N, int K) {
    __shared__ bf16 As[128 * 32];
    __shared__ bf16 Bs[128 * 32];

    const int t = threadIdx.x;
    const int lane = t & 63;
    const int w = t >> 6;
    const int wm = w >> 1, wn = w & 1;
    const int m0 = blockIdx.y * 128, n0 = blockIdx.x * 128;

    const int srow = lane >> 2;                       // row within 16-row chunk
    const int sg   = lane & 3;                        // LDS slot (fixed by lane)
    const int scol = (sg ^ ((srow >> 1) & 3)) * 8;    // swizzled source k-group

    f32x4 acc[4][4];
#pragma unroll
    for (int i = 0; i < 4; i++)
#pragma unroll
        for (int j = 0; j < 4; j++) acc[i][j] = (f32x4)0.f;

    const int lr = lane & 15;
    const int lq = lane >> 4;
    const int slotr = (lq ^ ((lr >> 1) & 3)) * 8;     // reader's swizzled slot

    for (int k0 = 0; k0 < K; k0 += 32) {
#pragma unroll
        for (int s = 0; s < 2; s++) {
            const int c = w * 2 + s;
            gld_lds16(A + (size_t)(m0 + c * 16 + srow) * K + k0 + scol, As + c * 512);
            gld_lds16(BT + (size_t)(n0 + c * 16 + srow) * K + k0 + scol, Bs + c * 512);
        }
        __syncthreads();
        short8 af[4], bfv[4];
#pragma unroll
        for (int i = 0; i < 4; i++)
            af[i] = *(const short8*)(As + (wm * 64 + i * 16 + lr) * 32 + slotr);
#pragma unroll
        for (int j = 0; j < 4; j++)
            bfv[j] = *(const short8*)(Bs + (wn * 64 + j * 16 + lr) * 32 + slotr);
#pragma unroll
        for (int i = 0; i < 4; i++)
#pragma unroll
            for (int j = 0; j < 4; j++)
                acc[i][j] = __builtin_amdgcn_mfma_f32_16x16x32_bf16(af[i], bfv[j],
                                                                    acc[i][j], 0, 0, 0);
        __syncthreads();
    }

    if (MODE == 0) {
#pragma unroll
        for (int j = 0; j < 4; j++) {
            const int col = n0 + wn * 64 + j * 16 + lr;
            const float bj = b0[col];
#pragma unroll
            for (int i = 0; i < 4; i++) {
                const int row = m0 + wm * 64 + i * 16 + lq * 4;
#pragma unroll
                for (int r = 0; r < 4; r++)
                    Yf[(size_t)(row + r) * N + col] = acc[i][j][r] + bj;
            }
        }
    } else if (n0 < 2560) {
        // Q or K region: bias + RoPE (pair exchange via shfl_xor lane^1)
        bf16* outp; const float* bias; int ldc, c0; float oscale;
        if (n0 < 2048) { outp = Yq; bias = b0; ldc = 2048; c0 = n0;
                         oscale = 0.08838834764831845f; }   // 1/sqrt(128) prefold
        else           { outp = Yk; bias = b1; ldc = 512;  c0 = n0 - 2048;
                         oscale = 1.0f; }
#pragma unroll
        for (int j = 0; j < 4; j++) {
            const int col = c0 + wn * 64 + j * 16 + lr;
            const float bj = bias[col];
            const int d2 = (col & 127) >> 1;
            const bool odd = col & 1;
            const float freq = __expf(-0.14384103622589045f * (float)d2); // ln(1e4)*2/128
#pragma unroll
            for (int i = 0; i < 4; i++) {
                const int row = m0 + wm * 64 + i * 16 + lq * 4;
#pragma unroll
                for (int r = 0; r < 4; r++) {
                    const float v = acc[i][j][r] + bj;
                    const float p = __shfl_xor(v, 1, 64);
                    const float ang = (float)((row + r) & (SS - 1)) * freq;
                    float sn, cs;
                    __sincosf(ang, &sn, &cs);
                    const float o = odd ? (p * sn + v * cs) : (v * cs - p * sn);
                    outp[(size_t)(row + r) * ldc + col] = toB(o * oscale);
                }
            }
        }
    } else {
        // V region: bias, store TRANSPOSED Yv[b][hkv][d][s] (4 s-consecutive
        // bf16 packed per 8B store; 128-row tiles never straddle the b split)
#pragma unroll
        for (int j = 0; j < 4; j++) {
            const int colv = (n0 - 2560) + wn * 64 + j * 16 + lr;   // 0..511
            const float bj = b2[colv];
            const int hv = colv >> 7, d = colv & 127;
#pragma unroll
            for (int i = 0; i < 4; i++) {
                const int row = m0 + wm * 64 + i * 16 + lq * 4;
                const int bb2 = row >> 11, sloc = row & (SS - 1);
                bf16 pk[4];
#pragma unroll
                for (int r = 0; r < 4; r++) pk[r] = toB(acc[i][j][r] + bj);
                *(uint2*)(Yv + (((size_t)bb2 * NKV + hv) * HD + d) * SS + sloc) =
                    *(const uint2*)pk;
            }
        }
    }
}

// ---------------------------------------------------------------------------
// MFMA flash attention, windowed causal, GQA. Block = 4 waves = 64 queries;
// wave-private online softmax; 64-key chunks. Q pre-scaled by 1/sqrt(HD).
// K staged [key][d] with 16-slot XOR swizzle; V comes in pre-transposed
// global Vt_g[b][hkv][d][s], staged [d][key] with 8-slot XOR swizzle --
// all fragment reads conflict-free, zero scalar LDS transpose work.
// IN-PLACE: Oout aliases Q (block reads its own 64 rows up front).
// ---------------------------------------------------------------------------
__global__ __launch_bounds__(256) void attn_mfma(const bf16* __restrict__ Q,
                                                 const bf16* __restrict__ K,
                                                 const bf16* __restrict__ Vt_g,
                                                 bf16* __restrict__ Oout) {
    __shared__ bf16 Ks[64 * 128];      // [key][slot]  16 KB, swizzled
    __shared__ bf16 Vt[128 * 64];      // [d][slot]    16 KB, swizzled
    __shared__ bf16 Ps[4 * 16 * 72];   // per-wave P   9 KB

    const int t = threadIdx.x;
    const int lane = t & 63;
    const int w = t >> 6;
    const int q0 = blockIdx.x * 64;
    const int h = blockIdx.y;
    const int b = blockIdx.z;
    const int hkv = h >> 2;
    const int lr = lane & 15;
    const int lq = lane >> 4;

    // Q fragments (pre-scaled in GEMM epilogue)
    short8 aq[4];
    {
        const int q = q0 + w * 16 + lr;
        const bf16* qp = Q + (((size_t)b * SS + q) * NQ + h) * HD + lq * 8;
#pragma unroll
        for (int ks = 0; ks < 4; ks++) aq[ks] = *(const short8*)(qp + ks * 32);
    }

    f32x4 Oa[8];
#pragma unroll
    for (int nb = 0; nb < 8; nb++) Oa[nb] = (f32x4)0.f;
    float mprev[4] = {-3.0e38f, -3.0e38f, -3.0e38f, -3.0e38f};
    float lsum[4] = {0.f, 0.f, 0.f, 0.f};

    bf16* Pw = Ps + w * 16 * 72;
    const int jstart = (q0 >= WINDOW) ? (q0 - WINDOW) : 0;
    const bf16* Vrow = Vt_g + ((size_t)b * NKV + hkv) * HD * SS;

    for (int c0 = jstart; c0 <= q0; c0 += 64) {
        __syncthreads();
        // stage K: wave w -> key rows [w*16, w*16+16), swizzled slots
#pragma unroll
        for (int s = 0; s < 4; s++) {
            const int kr = w * 16 + s * 4 + (lane >> 4);       // key row
            const int sl = lane & 15;
            const int g = (sl & 8) | ((sl & 7) ^ (kr & 7));    // source k-group
            gld_lds16(K + (((size_t)b * SS + c0 + kr) * NKV + hkv) * HD + g * 8,
                      Ks + (w * 16 + s * 4) * 128);
        }
        // stage V: wave w -> d rows [w*32, w*32+32), swizzled slots
#pragma unroll
        for (int s = 0; s < 4; s++) {
            const int dr = w * 32 + s * 8 + (lane >> 3);       // d row
            const int sl = lane & 7;
            const int g = sl ^ (dr & 7);                       // source key-group
            gld_lds16(Vrow + (size_t)dr * SS + c0 + g * 8,
                      Vt + (w * 32 + s * 8) * 64);
        }
        __syncthreads();

        // QK^T: 16q x 64k, C-layout (col=key=lr, row=q=lq*4+r)
        f32x4 sa[4];
#pragma unroll
        for (int nb = 0; nb < 4; nb++) sa[nb] = (f32x4)0.f;
#pragma unroll
        for (int ks = 0; ks < 4; ks++) {
#pragma unroll
            for (int nb = 0; nb < 4; nb++) {
                const int row = nb * 16 + lr;
                const int g = ks * 4 + lq;
                const int slot = (g & 8) | ((g & 7) ^ (row & 7));
                short8 bk = *(const short8*)(Ks + row * 128 + slot * 8);
                sa[nb] = __builtin_amdgcn_mfma_f32_16x16x32_bf16(aq[ks], bk, sa[nb], 0, 0, 0);
            }
        }

        // online softmax (rows lq*4+r; reduce across lane bits 0-3)
        const int rowb = q0 + w * 16 + lq * 4;
        const bool needmask = !((c0 + 63 <= q0 + w * 16) &&
                                (q0 + w * 16 + 15 - c0 <= WINDOW));
        float pr[4][4], alpha[4];
#pragma unroll
        for (int r = 0; r < 4; r++) {
            const int row = rowb + r;
            float sv[4];
            float mx = -3.0e38f;
            if (needmask) {
#pragma unroll
                for (int nb = 0; nb < 4; nb++) {
                    const int col = c0 + nb * 16 + lr;
                    const bool valid = (col <= row) && (row - col <= WINDOW);
                    sv[nb] = valid ? sa[nb][r] : -3.0e38f;
                    mx = fmaxf(mx, sv[nb]);
                }
            } else {
#pragma unroll
                for (int nb = 0; nb < 4; nb++) {
                    sv[nb] = sa[nb][r];
                    mx = fmaxf(mx, sv[nb]);
                }
            }
#pragma unroll
            for (int off = 1; off < 16; off <<= 1) mx = fmaxf(mx, __shfl_xor(mx, off, 64));
            const float mn = fmaxf(fmaxf(mprev[r], mx), -1.0e30f);
            alpha[r] = __expf(mprev[r] - mn);
            mprev[r] = mn;
            float rs = 0.f;
#pragma unroll
            for (int nb = 0; nb < 4; nb++) {
                const float p = __expf(sv[nb] - mn);
                pr[r][nb] = p;
                rs += p;
            }
#pragma unroll
            for (int off = 1; off < 16; off <<= 1) rs += __shfl_xor(rs, off, 64);
            lsum[r] = lsum[r] * alpha[r] + rs;
        }

        // P: C-layout -> wave-private LDS [q][key] (stride 72)
#pragma unroll
        for (int r = 0; r < 4; r++)
#pragma unroll
            for (int nb = 0; nb < 4; nb++)
                Pw[(lq * 4 + r) * 72 + nb * 16 + lr] = toB(pr[r][nb]);

        // rescale O, then PV: A=P (b128 from Pw), B=V (b128 from swizzled Vt)
#pragma unroll
        for (int nb = 0; nb < 8; nb++)
#pragma unroll
            for (int r = 0; r < 4; r++) Oa[nb][r] *= alpha[r];
#pragma unroll
        for (int ks = 0; ks < 2; ks++) {
            short8 pa = *(const short8*)(Pw + lr * 72 + ks * 32 + lq * 8);
#pragma unroll
            for (int nb = 0; nb < 8; nb++) {
                const int d = nb * 16 + lr;
                const int g = ks * 4 + lq;
                const int slot = g ^ (d & 7);
                short8 bv = *(const short8*)(Vt + d * 64 + slot * 8);
                Oa[nb] = __builtin_amdgcn_mfma_f32_16x16x32_bf16(pa, bv, Oa[nb], 0, 0, 0);
            }
        }
    }

    // epilogue: normalize + store (in-place over this block's own Q rows)
    float linv[4];
#pragma unroll
    for (int r = 0; r < 4; r++) linv[r] = 1.f / lsum[r];
    const int rowb = q0 + w * 16 + lq * 4;
#pragma unroll
    for (int nb = 0; nb < 8; nb++)
#pragma unroll
        for (int r = 0; r < 4; r++)
            Oout[(((size_t)b * SS + rowb + r) * NQ + h) * HD + nb * 16 + lr] =
                toB(Oa[nb][r] * linv[r]);
}

// ---------------------------------------------------------------------------
extern "C" void kernel_launch(void* const* d_in, const int* in_sizes, int n_in,
                              void* d_out, int out_size, void* d_ws, size_t ws_size,
                              hipStream_t stream) {
    const float* x  = (const float*)d_in[0];
    const float* Wq = (const float*)d_in[1];
    const float* bq = (const float*)d_in[2];
    const float* Wk = (const float*)d_in[3];
    const float* bk = (const float*)d_in[4];
    const float* Wv = (const float*)d_in[5];
    const float* bv = (const float*)d_in[6];
    const float* Wo = (const float*)d_in[7];
    const float* bo = (const float*)d_in[8];
    float* out = (float*)d_out;

    const int M   = BB * SS;       // 4096
    const int DQ  = NQ * HD;       // 2048
    const int DKV = NKV * HD;      // 512
    const int NPK = DQ + 2 * DKV;  // 3072

    bf16* xb     = (bf16*)d_ws;                       // 4096*2048
    bf16* WqkvT  = xb + (size_t)M * EE;               // 3072*2048
    bf16* WoT    = WqkvT + (size_t)NPK * EE;          // 2048*2048
    bf16* Qb     = WoT + (size_t)EE * DQ;             // 4096*2048 (attn out in-place)
    bf16* Kb     = Qb + (size_t)M * DQ;               // 4096*512  [b,s,hkv,d]
    bf16* Vtg    = Kb + (size_t)M * DKV;              // 4096*512  [b,hkv,d,s]

    convert_bf16<<<(M * EE / 4 + 255) / 256, 256, 0, stream>>>(x, xb, M * EE);
    convert_transpose_qkv<<<dim3(NPK / 32, EE / 32), 256, 0, stream>>>(Wq, Wk, Wv, WqkvT);
    convert_transpose<<<dim3(DQ / 32, DQ / 32), 256, 0, stream>>>(Wo, WoT, DQ, EE);

    // fused QKV projection + bias + RoPE + Q-prescale + V-transpose (MFMA)
    mfma_gemm<1><<<dim3(NPK / 128, M / 128), 256, 0, stream>>>(
        xb, WqkvT, bq, bk, bv, nullptr, Qb, Kb, Vtg, M, NPK, EE);

    attn_mfma<<<dim3(SS / 64, NQ, BB), 256, 0, stream>>>(Qb, Kb, Vtg, Qb);

    mfma_gemm<0><<<dim3(EE / 128, M / 128), 256, 0, stream>>>(
        Qb, WoT, bo, nullptr, nullptr, out, nullptr, nullptr, nullptr, M, EE, DQ);
}